// Round 12
// baseline (490.131 us; speedup 1.0000x reference)
//
#include <hip/hip_runtime.h>

#define N_NODES 100000
#define P_PAIRS 3200000
#define IN_F    19
#define OUT_F   64
#define BN_EPS  1e-5f
#define SLOPE   0.01f
#define BSHIFT  8       // 256 keys per bucket
#define BUCKETS 391     // ceil(N_NODES / 256)
#define CAP     9000    // staging capacity per bucket (mean 8184, sd ~90)
#define CHUNK_P 3200    // pairs per bucket1 block (P / 3200 = 1000 blocks)
#define NCH     4       // channel chunks
#define CH_F    16      // channels per chunk (32 B rows, 3.2 MB table -> L2-resident)
#define HOP_UNITS 25000 // 6250 segment-groups x 4 chunks

typedef __attribute__((ext_vector_type(8))) unsigned short u16x8;
typedef __attribute__((ext_vector_type(8))) short bf16x8;
typedef __attribute__((ext_vector_type(4))) float f32x4;

__device__ __forceinline__ float bf2f(unsigned short h) {
    return __uint_as_float(((unsigned)h) << 16);
}
__device__ __forceinline__ unsigned short f2bf(float f) {
    unsigned u = __float_as_uint(f);
    return (unsigned short)((u + 0x7FFF + ((u >> 16) & 1)) >> 16);  // RNE
}

// ---------------------------------------------------------------------------
// K1: xw = x @ W_conv -> bf16 chunk-major [4][N][16]. Weight column in VGPRs,
// grid-stride over node pairs (ILP + full-line chunk stores).
// ---------------------------------------------------------------------------
__global__ __launch_bounds__(256) void k_input_gemm(
    const float* __restrict__ x, const float* __restrict__ Wc,
    unsigned short* __restrict__ xwb)
{
    int lane = threadIdx.x & 63;
    float w[IN_F];
    #pragma unroll
    for (int k = 0; k < IN_F; ++k) w[k] = Wc[k * OUT_F + lane];
    size_t coff = (size_t)(lane >> 4) * (N_NODES * CH_F) + (lane & 15);

    int gw = (blockIdx.x * 256 + threadIdx.x) >> 6;
    int nw = gridDim.x * 4;
    for (int n = gw * 2; n < N_NODES; n += nw * 2) {   // N even
        const float* xr0 = x + (size_t)n * IN_F;
        const float* xr1 = xr0 + IN_F;
        float a0 = 0.f, a1 = 0.f;
        #pragma unroll
        for (int k = 0; k < IN_F; ++k) {
            a0 += xr0[k] * w[k];
            a1 += xr1[k] * w[k];
        }
        xwb[coff + (size_t)n * CH_F]       = f2bf(a0);
        xwb[coff + (size_t)(n + 1) * CH_F] = f2bf(a1);
    }
}

// ---------------------------------------------------------------------------
// K2: combined bucket phase 1 — BOTH sides in one pass over the pairs.
// Block-level counting sort into two LDS scratches, burst-flush bucket runs.
// stage entry: (key & 255) << 17 | value  (both ids < 2^17)
// ---------------------------------------------------------------------------
__global__ __launch_bounds__(512) void k_bucket1_both(
    const int* __restrict__ ni, const int* __restrict__ ei,
    int* __restrict__ curE, int* __restrict__ curN,
    unsigned int* __restrict__ stageE, unsigned int* __restrict__ stageN)
{
    __shared__ int histE[BUCKETS], histN[BUCKETS];
    __shared__ int cE[BUCKETS], cN[BUCKETS];
    __shared__ int gbE[BUCKETS], gbN[BUCKETS];
    __shared__ int s[512];
    __shared__ unsigned int scrE[CHUNK_P], scrN[CHUNK_P];
    int t = threadIdx.x;
    for (int b = t; b < BUCKETS; b += 512) { histE[b] = 0; histN[b] = 0; }
    __syncthreads();
    int p0 = blockIdx.x * CHUNK_P;
    for (int i = t; i < CHUNK_P; i += 512) {
        atomicAdd(&histE[ei[p0 + i] >> BSHIFT], 1);
        atomicAdd(&histN[ni[p0 + i] >> BSHIFT], 1);
    }
    __syncthreads();
    s[t] = (t < BUCKETS) ? histE[t] : 0;
    __syncthreads();
    for (int off = 1; off < 512; off <<= 1) {
        int tmp = (t >= off) ? s[t - off] : 0;
        __syncthreads();
        if (t >= off) s[t] += tmp;
        __syncthreads();
    }
    if (t < BUCKETS) {
        int c = histE[t];
        gbE[t] = (c > 0) ? atomicAdd(&curE[t], c) : 0;
        cE[t] = s[t] - c;
    }
    __syncthreads();
    s[t] = (t < BUCKETS) ? histN[t] : 0;
    __syncthreads();
    for (int off = 1; off < 512; off <<= 1) {
        int tmp = (t >= off) ? s[t - off] : 0;
        __syncthreads();
        if (t >= off) s[t] += tmp;
        __syncthreads();
    }
    if (t < BUCKETS) {
        int c = histN[t];
        gbN[t] = (c > 0) ? atomicAdd(&curN[t], c) : 0;
        cN[t] = s[t] - c;
    }
    __syncthreads();
    for (int i = t; i < CHUNK_P; i += 512) {
        int n = ni[p0 + i];
        int e = ei[p0 + i];
        int pE = atomicAdd(&cE[e >> BSHIFT], 1);
        scrE[pE] = ((unsigned)(e & 255) << 17) | (unsigned)n;
        int pN = atomicAdd(&cN[n >> BSHIFT], 1);
        scrN[pN] = ((unsigned)(n & 255) << 17) | (unsigned)e;
    }
    __syncthreads();
    int grp = t >> 4, l16 = t & 15;
    for (int b = grp; b < BUCKETS; b += 32) {
        int c = histE[b];
        if (c > 0) {
            int ls = cE[b] - c;
            int gs = gbE[b];
            size_t sb = (size_t)b * CAP;
            for (int j = l16; j < c; j += 16)
                if (gs + j < CAP) stageE[sb + gs + j] = scrE[ls + j];
        }
        c = histN[b];
        if (c > 0) {
            int ls = cN[b] - c;
            int gs = gbN[b];
            size_t sb = (size_t)b * CAP;
            for (int j = l16; j < c; j += 16)
                if (gs + j < CAP) stageN[sb + gs + j] = scrN[ls + j];
        }
    }
}

// ---------------------------------------------------------------------------
// K3: mini-scan of bucket totals -> adj base offsets. block 0: E, block 1: N
// (curE/curN and baseE/baseN are laid out contiguously).
// ---------------------------------------------------------------------------
__global__ __launch_bounds__(512) void k_minscan(
    const int* __restrict__ curAll, int* __restrict__ baseAll)
{
    __shared__ int s[512];
    const int* cur = curAll + blockIdx.x * BUCKETS;
    int* base = baseAll + blockIdx.x * BUCKETS;
    int t = threadIdx.x;
    int v = (t < BUCKETS) ? cur[t] : 0;
    s[t] = v;
    __syncthreads();
    for (int off = 1; off < 512; off <<= 1) {
        int tmp = (t >= off) ? s[t - off] : 0;
        __syncthreads();
        s[t] += tmp;
        __syncthreads();
    }
    if (t < BUCKETS) base[t] = s[t] - v;   // exclusive
}

// ---------------------------------------------------------------------------
// K4: bucket phase 2, both sides fused — grid = 2*BUCKETS.
// ---------------------------------------------------------------------------
__global__ __launch_bounds__(512) void k_bucket2_both(
    const unsigned int* __restrict__ stageE, const unsigned int* __restrict__ stageN,
    const int* __restrict__ curE, const int* __restrict__ curN,
    const int* __restrict__ baseE, const int* __restrict__ baseN,
    int* __restrict__ adjE, int* __restrict__ adjN,
    int* __restrict__ offE, int* __restrict__ lenE,
    int* __restrict__ offN, int* __restrict__ lenN)
{
    __shared__ int cnt[256];
    __shared__ int s[256];
    __shared__ int cur_l[256];
    int b = blockIdx.x;
    int nodeSide = (b >= BUCKETS) ? 1 : 0;
    if (nodeSide) b -= BUCKETS;
    const unsigned int* stage = nodeSide ? stageN : stageE;
    const int* cur  = nodeSide ? curN : curE;
    const int* base = nodeSide ? baseN : baseE;
    int* adj  = nodeSide ? adjN : adjE;
    int* offK = nodeSide ? offN : offE;
    int* lenK = nodeSide ? lenN : lenE;

    int t = threadIdx.x;
    int m = cur[b]; if (m > CAP) m = CAP;
    size_t sbase = (size_t)b * CAP;
    if (t < 256) cnt[t] = 0;
    __syncthreads();
    for (int i = t; i < m; i += 512)
        atomicAdd(&cnt[stage[sbase + i] >> 17], 1);
    __syncthreads();
    int c = 0;
    if (t < 256) { c = cnt[t]; s[t] = c; }
    __syncthreads();
    for (int off = 1; off < 256; off <<= 1) {
        int tmp = 0;
        if (t < 256 && t >= off) tmp = s[t - off];
        __syncthreads();
        if (t < 256 && t >= off) s[t] += tmp;
        __syncthreads();
    }
    if (t < 256) {
        int keyoff = base[b] + s[t] - c;
        int k = (b << BSHIFT) + t;
        if (k < N_NODES) { offK[k] = keyoff; lenK[k] = c; }
        cur_l[t] = keyoff;
    }
    __syncthreads();
    for (int i = t; i < m; i += 512) {
        unsigned v = stage[sbase + i];
        int kl = v >> 17;
        int pos = atomicAdd(&cur_l[kl], 1);
        adj[pos] = (int)(v & 0x1FFFF);
    }
}

// ---------------------------------------------------------------------------
// K5: fused hop, persistent blocks (grid stride 2048 ≡ 0 mod 8 keeps the
// chunk↔XCD pinning: unit&7 constant per block). Depth-2 adj prefetch
// decouples the adj->gather dependent chain.
// lane = (seg 2b, row-slot 3b, chan-half 1b); unit = (sb, chunk).
// ---------------------------------------------------------------------------
__global__ __launch_bounds__(256) void k_hop(
    const int* __restrict__ adj, const int* __restrict__ offK,
    const int* __restrict__ lenK, const unsigned short* __restrict__ tin_base,
    unsigned short* __restrict__ tout_base, const float* __restrict__ bcc)
{
    int lane = threadIdx.x & 63;
    int wv = threadIdx.x >> 6;
    int es  = lane >> 4;
    int sub = (lane >> 1) & 7;
    int cg  = lane & 1;

    for (int u = blockIdx.x; u < HOP_UNITS; u += gridDim.x) {
        int chunk = (u & 6) >> 1;
        int sb = ((u >> 3) << 1) | (u & 1);      // 0..6249
        const unsigned short* tin = tin_base + (size_t)chunk * (N_NODES * CH_F);
        unsigned short* tout = tout_base + (size_t)chunk * (N_NODES * CH_F);

        int k = (sb * 4 + wv) * 4 + es;
        int len = lenK[k];
        int start = offK[k];
        int end = start + len;

        float acc[8];
        #pragma unroll
        for (int j = 0; j < 8; ++j) acc[j] = 0.f;

        // clamped prefetch index (never OOB; prefetched-but-unconsumed ok)
        int safe = end - 1;
        if (safe < 0) safe = 0;
        if (safe >= P_PAIRS) safe = P_PAIRS - 1;

        int i = start + sub;
        int p0 = (i <= safe) ? i : safe;
        int p1 = (i + 8 <= safe) ? i + 8 : safe;
        int a0 = __builtin_nontemporal_load(&adj[p0]);
        int a1 = __builtin_nontemporal_load(&adj[p1]);
        for (; i < end; i += 8) {
            int cur = a0;
            a0 = a1;
            int pn = (i + 16 <= safe) ? i + 16 : safe;
            a1 = __builtin_nontemporal_load(&adj[pn]);   // 2 rounds ahead
            u16x8 v = *(const u16x8*)(tin + (size_t)cur * CH_F + cg * 8);
            #pragma unroll
            for (int j = 0; j < 8; ++j) acc[j] += bf2f(v[j]);
        }
        #pragma unroll
        for (int m = 2; m < 16; m <<= 1) {       // reduce over sub bits
            #pragma unroll
            for (int j = 0; j < 8; ++j) acc[j] += __shfl_xor(acc[j], m, 64);
        }
        if ((lane & 14) == 0) {                  // sub == 0
            float sc = (len > 0) ? 1.f / (float)len : 0.f;
            u16x8 o;
            if (bcc) {
                #pragma unroll
                for (int j = 0; j < 8; ++j)
                    o[j] = f2bf(acc[j] * sc + bcc[chunk * CH_F + cg * 8 + j]);
            } else {
                #pragma unroll
                for (int j = 0; j < 8; ++j) o[j] = f2bf(acc[j] * sc);
            }
            __builtin_nontemporal_store(o, (u16x8*)(tout + (size_t)k * CH_F + cg * 8));
        }
    }
}

// ---------------------------------------------------------------------------
// K6: MLP via MFMA: h = cv @ Wm + bm  (+ BN partials, block-reduced in LDS)
// ---------------------------------------------------------------------------
__global__ __launch_bounds__(256) void k_mlp_mfma(
    const unsigned short* __restrict__ cvb, const float* __restrict__ Wm,
    const float* __restrict__ bm, float* __restrict__ h,
    float* __restrict__ bns)
{
    __shared__ float red[128];             // [sum 64][sumsq 64]
    if (threadIdx.x < 128) red[threadIdx.x] = 0.f;
    __syncthreads();

    int lane = threadIdx.x & 63;
    int q = lane >> 4;
    int c = lane & 15;

    bf16x8 bf[4][2];
    #pragma unroll
    for (int t = 0; t < 4; ++t)
        #pragma unroll
        for (int kh = 0; kh < 2; ++kh)
            #pragma unroll
            for (int j = 0; j < 8; ++j)
                bf[t][kh][j] = (short)f2bf(Wm[(kh * 32 + q * 8 + j) * OUT_F + t * 16 + c]);
    float bmv[4];
    #pragma unroll
    for (int t = 0; t < 4; ++t) bmv[t] = bm[t * 16 + c];

    float s[4], s2[4];
    #pragma unroll
    for (int t = 0; t < 4; ++t) { s[t] = 0.f; s2[t] = 0.f; }

    int gw = (blockIdx.x * 256 + threadIdx.x) >> 6;
    int nw = gridDim.x * 4;
    const int NT = N_NODES / 16;
    for (int tile = gw; tile < NT; tile += nw) {
        int r0 = tile * 16;
        size_t rowoff = (size_t)(r0 + c) * CH_F + (q & 1) * 8;
        bf16x8 a0 = *(const bf16x8*)(cvb + (size_t)(q >> 1) * (N_NODES * CH_F) + rowoff);
        bf16x8 a1 = *(const bf16x8*)(cvb + (size_t)(2 + (q >> 1)) * (N_NODES * CH_F) + rowoff);
        #pragma unroll
        for (int t = 0; t < 4; ++t) {
            f32x4 acc = {0.f, 0.f, 0.f, 0.f};
            acc = __builtin_amdgcn_mfma_f32_16x16x32_bf16(a0, bf[t][0], acc, 0, 0, 0);
            acc = __builtin_amdgcn_mfma_f32_16x16x32_bf16(a1, bf[t][1], acc, 0, 0, 0);
            #pragma unroll
            for (int r = 0; r < 4; ++r) {
                float hv = acc[r] + bmv[t];
                h[(size_t)(r0 + q * 4 + r) * OUT_F + t * 16 + c] = hv;
                s[t]  += hv;
                s2[t] += hv * hv;
            }
        }
    }
    #pragma unroll
    for (int t = 0; t < 4; ++t) {
        #pragma unroll
        for (int m = 16; m < 64; m <<= 1) {
            s[t]  += __shfl_xor(s[t],  m, 64);
            s2[t] += __shfl_xor(s2[t], m, 64);
        }
    }
    if (lane < 16) {
        #pragma unroll
        for (int t = 0; t < 4; ++t) {
            atomicAdd(&red[t * 16 + lane], s[t]);
            atomicAdd(&red[64 + t * 16 + lane], s2[t]);
        }
    }
    __syncthreads();
    if (threadIdx.x < 128) atomicAdd(&bns[threadIdx.x], red[threadIdx.x]);
}

// ---------------------------------------------------------------------------
// K7: BN normalize + LeakyReLU + residual + LeakyReLU (weights in VGPRs)
// ---------------------------------------------------------------------------
__global__ __launch_bounds__(256) void k_final(
    const float* __restrict__ x, const float* __restrict__ Wr,
    const float* __restrict__ br, const float* __restrict__ bns,
    const float* __restrict__ gamma, const float* __restrict__ beta,
    float* __restrict__ out)
{
    int lane = threadIdx.x & 63;
    float w[IN_F];
    #pragma unroll
    for (int k = 0; k < IN_F; ++k) w[k] = Wr[k * OUT_F + lane];
    const float inv_n = 1.f / (float)N_NODES;
    float mean = bns[lane] * inv_n;
    float var  = bns[64 + lane] * inv_n - mean * mean;
    float rstd = rsqrtf(var + BN_EPS);
    float g = gamma[lane], bt = beta[lane];
    float rb = br[lane];

    int gw = (blockIdx.x * 256 + threadIdx.x) >> 6;
    int nw = gridDim.x * 4;
    for (int n = gw * 2; n < N_NODES; n += nw * 2) {
        const float* xr0 = x + (size_t)n * IN_F;
        const float* xr1 = xr0 + IN_F;
        float r0 = rb, r1 = rb;
        #pragma unroll
        for (int k = 0; k < IN_F; ++k) {
            r0 += xr0[k] * w[k];
            r1 += xr1[k] * w[k];
        }
        float hv0 = out[(size_t)n * OUT_F + lane];
        float hv1 = out[(size_t)(n + 1) * OUT_F + lane];
        float a0 = g * (hv0 - mean) * rstd + bt;
        float a1 = g * (hv1 - mean) * rstd + bt;
        a0 = (a0 >= 0.f) ? a0 : SLOPE * a0;
        a1 = (a1 >= 0.f) ? a1 : SLOPE * a1;
        float y0 = a0 + r0;
        float y1 = a1 + r1;
        out[(size_t)n * OUT_F + lane]       = (y0 >= 0.f) ? y0 : SLOPE * y0;
        out[(size_t)(n + 1) * OUT_F + lane] = (y1 >= 0.f) ? y1 : SLOPE * y1;
    }
}

// ---------------------------------------------------------------------------
extern "C" void kernel_launch(void* const* d_in, const int* in_sizes, int n_in,
                              void* d_out, int out_size, void* d_ws, size_t ws_size,
                              hipStream_t stream) {
    const float* x     = (const float*)d_in[0];
    const int*   hidx  = (const int*)d_in[1];
    const int*   ni    = hidx;               // row 0: node idx
    const int*   ei    = hidx + P_PAIRS;     // row 1: edge idx
    const float* Wc    = (const float*)d_in[2];
    const float* bc    = (const float*)d_in[3];
    const float* Wm    = (const float*)d_in[4];
    const float* bm    = (const float*)d_in[5];
    const float* gamma = (const float*)d_in[6];
    const float* beta  = (const float*)d_in[7];
    const float* Wr    = (const float*)d_in[8];
    const float* br    = (const float*)d_in[9];
    float* out = (float*)d_out;

    // --- ws (~94 MB of the 256 MB workspace), no aliasing:
    int* adjE = (int*)d_ws;                                  // P
    int* adjN = adjE + P_PAIRS;                              // P
    unsigned int* stageE = (unsigned int*)(adjN + P_PAIRS);  // BUCKETS*CAP
    unsigned int* stageN = stageE + (size_t)BUCKETS * CAP;   // BUCKETS*CAP
    unsigned short* xwb = (unsigned short*)(stageN + (size_t)BUCKETS * CAP); // [4][N][16]
    unsigned short* efb = xwb + (size_t)NCH * N_NODES * CH_F;
    unsigned short* cvb = efb + (size_t)NCH * N_NODES * CH_F;
    float* bns = (float*)(cvb + (size_t)NCH * N_NODES * CH_F);
    int* curE  = (int*)(bns + 128);          // curE, curN contiguous
    int* curN  = curE + BUCKETS;
    int* baseE = curN + BUCKETS;             // baseE, baseN contiguous
    int* baseN = baseE + BUCKETS;
    int* offE  = baseN + BUCKETS;
    int* lenE  = offE + N_NODES;
    int* offN  = lenE + N_NODES;
    int* lenN  = offN + N_NODES;

    // zero bns + curE + curN (contiguous)
    hipMemsetAsync(bns, 0, (128 + 2 * BUCKETS) * sizeof(int), stream);

    k_input_gemm<<<256, 256, 0, stream>>>(x, Wc, xwb);

    k_bucket1_both<<<P_PAIRS / CHUNK_P, 512, 0, stream>>>(ni, ei, curE, curN, stageE, stageN);
    k_minscan<<<2, 512, 0, stream>>>(curE, baseE);
    k_bucket2_both<<<2 * BUCKETS, 512, 0, stream>>>(
        stageE, stageN, curE, curN, baseE, baseN,
        adjE, adjN, offE, lenE, offN, lenN);

    k_hop<<<2048, 256, 0, stream>>>(adjE, offE, lenE, xwb, efb, (const float*)nullptr);
    k_hop<<<2048, 256, 0, stream>>>(adjN, offN, lenN, efb, cvb, bc);

    k_mlp_mfma<<<256, 256, 0, stream>>>(cvb, Wm, bm, out, bns);
    k_final<<<256, 256, 0, stream>>>(x, Wr, br, bns, gamma, beta, out);
}